// Round 13
// baseline (354.351 us; speedup 1.0000x reference)
//
#include <hip/hip_runtime.h>

#define N_NODES 100000
#define N_EDGES 3200000
#define CH      12500      // edges per chunk (C1/C3)
#define C_NB    256        // chunks; C_NB*CH == N_EDGES exactly
#define NBUCK   782        // ceil(N_NODES/128)
#define G1_NB   1563       // ceil(N_NODES/64)
#define G1_HALF 782        // gemm1 blocks in launch A (rest in B)
#define BPAD    1024       // per-bucket padding headroom (max row-pads 7*128=896)

typedef unsigned int uint;
typedef unsigned short ushort;

typedef __attribute__((ext_vector_type(8))) short short8;    // 8 bf16 (4 VGPRs)
typedef __attribute__((ext_vector_type(4))) float floatx4;   // MFMA C/D

static __device__ __forceinline__ ushort f2bf(float f) {     // RNE
    uint u = __float_as_uint(f);
    u += 0x7fffu + ((u >> 16) & 1u);
    return (ushort)(u >> 16);
}
static __device__ __forceinline__ float bf2f(ushort h) {
    return __uint_as_float(((uint)h) << 16);
}

// ---------------- gemm1 block body (MFMA, 64 rows x 64 cols, 4 waves, no LDS) ----------------
static __device__ __forceinline__ void gemm1_block(int bid, int tid,
                                                   const float* __restrict__ X,
                                                   const ushort* __restrict__ W1f,
                                                   ushort* __restrict__ H1) {
    const int wave = tid >> 6;
    const int lane = tid & 63;
    const int arow = bid * 64 + wave * 16 + (lane & 15);
    const bool valid = arow < N_NODES;
    const float* xr = X + (long)arow * 512 + ((lane >> 4) << 3);
    const short8* bb = reinterpret_cast<const short8*>(W1f) + lane;

    floatx4 acc0 = {0.f, 0.f, 0.f, 0.f};
    floatx4 acc1 = {0.f, 0.f, 0.f, 0.f};
    floatx4 acc2 = {0.f, 0.f, 0.f, 0.f};
    floatx4 acc3 = {0.f, 0.f, 0.f, 0.f};

    for (int kt = 0; kt < 16; ++kt) {
        float4 ax0, ax1;
        if (valid) {
            ax0 = *reinterpret_cast<const float4*>(xr + kt * 32);
            ax1 = *reinterpret_cast<const float4*>(xr + kt * 32 + 4);
        } else {
            ax0 = make_float4(0.f, 0.f, 0.f, 0.f);
            ax1 = ax0;
        }
        uint4 ap;
        ap.x = (__float_as_uint(ax0.x) >> 16) | (__float_as_uint(ax0.y) & 0xffff0000u);
        ap.y = (__float_as_uint(ax0.z) >> 16) | (__float_as_uint(ax0.w) & 0xffff0000u);
        ap.z = (__float_as_uint(ax1.x) >> 16) | (__float_as_uint(ax1.y) & 0xffff0000u);
        ap.w = (__float_as_uint(ax1.z) >> 16) | (__float_as_uint(ax1.w) & 0xffff0000u);
        short8 a = *reinterpret_cast<short8*>(&ap);

        const short8* bk = bb + kt * 4 * 64;
        acc0 = __builtin_amdgcn_mfma_f32_16x16x32_bf16(a, bk[0 * 64], acc0, 0, 0, 0);
        acc1 = __builtin_amdgcn_mfma_f32_16x16x32_bf16(a, bk[1 * 64], acc1, 0, 0, 0);
        acc2 = __builtin_amdgcn_mfma_f32_16x16x32_bf16(a, bk[2 * 64], acc2, 0, 0, 0);
        acc3 = __builtin_amdgcn_mfma_f32_16x16x32_bf16(a, bk[3 * 64], acc3, 0, 0, 0);
    }

    const int mrow = bid * 64 + wave * 16 + (lane >> 4) * 4;
    const int ncol = lane & 15;
    #pragma unroll
    for (int r = 0; r < 4; ++r) {
        int orow = mrow + r;
        if (orow < N_NODES) {
            ushort* o = H1 + (long)orow * 64 + ncol;
            o[0]  = f2bf(acc0[r]);
            o[16] = f2bf(acc1[r]);
            o[32] = f2bf(acc2[r]);
            o[48] = f2bf(acc3[r]);
        }
    }
}

// ---------------- prep: w1cvt (blocks 0..127) + zero coarse_count ----------------
__global__ __launch_bounds__(256) void prep_kernel(const float* __restrict__ W1,
                                                   ushort* __restrict__ W1f,
                                                   int* __restrict__ cc) {
    if (blockIdx.x < 128) {
        int t = blockIdx.x * 256 + threadIdx.x;   // 0..32767
        int j = t & 7;
        int lane = (t >> 3) & 63;
        int tile = t >> 9;
        int kt = tile >> 2, nt = tile & 3;
        int k = kt * 32 + ((lane >> 4) << 3) + j;
        int n = nt * 16 + (lane & 15);
        W1f[t] = f2bf(W1[k * 64 + n]);
    } else {
        int i = (blockIdx.x - 128) * 256 + threadIdx.x;
        if (i < NBUCK) cc[i] = 0;
    }
}

// ---------------- C1: coarse hist (standalone) ----------------
__global__ __launch_bounds__(256) void c1_kernel(const int* __restrict__ row,
                                                 int* __restrict__ cc,
                                                 int* __restrict__ blockbase) {
    __shared__ int hist[NBUCK];
    const int blk = blockIdx.x;
    for (int i = threadIdx.x; i < NBUCK; i += 256) hist[i] = 0;
    __syncthreads();
    const int4* rp = reinterpret_cast<const int4*>(row + (long)blk * CH);
    for (int i = threadIdx.x; i < CH / 4; i += 256) {
        int4 r = rp[i];
        atomicAdd(&hist[r.x >> 7], 1);
        atomicAdd(&hist[r.y >> 7], 1);
        atomicAdd(&hist[r.z >> 7], 1);
        atomicAdd(&hist[r.w >> 7], 1);
    }
    __syncthreads();
    for (int i = threadIdx.x; i < NBUCK; i += 256) {
        int c = hist[i];
        int base = 0;
        if (c) base = atomicAdd(&cc[i], c);
        blockbase[blk * NBUCK + i] = base;
    }
}

// ---------------- C2: scan of 782 coarse counts ----------------
__global__ __launch_bounds__(1024) void c2_scan_kernel(const int* __restrict__ cc,
                                                       int* __restrict__ cptr) {
    __shared__ int sm[1024];
    const int tid = threadIdx.x;
    int v = (tid < NBUCK) ? cc[tid] : 0;
    sm[tid] = v;
    __syncthreads();
    #pragma unroll
    for (int off = 1; off < 1024; off <<= 1) {
        int t = (tid >= off) ? sm[tid - off] : 0;
        __syncthreads();
        sm[tid] += t;
        __syncthreads();
    }
    if (tid < NBUCK) cptr[tid] = sm[tid] - v;        // exclusive
    if (tid == NBUCK - 1) cptr[NBUCK] = sm[tid];     // total = N_EDGES
}

// ---------------- Launch A: C3 bucket scatter (blocks 0..C_NB-1) | gemm1 half 1 ----------------
__global__ __launch_bounds__(256) void fusedA_kernel(const int* __restrict__ row,
                                                     const int* __restrict__ col,
                                                     const float* __restrict__ val,
                                                     const int* __restrict__ cptr,
                                                     const int* __restrict__ blockbase,
                                                     int2* __restrict__ staging,
                                                     const float* __restrict__ X,
                                                     const ushort* __restrict__ W1f,
                                                     ushort* __restrict__ H1) {
    __shared__ int cnt[NBUCK];
    if (blockIdx.x < C_NB) {
        const int blk = blockIdx.x;
        for (int i = threadIdx.x; i < NBUCK; i += 256) cnt[i] = 0;
        __syncthreads();
        const long e0 = (long)blk * CH;
        const int4* rp = reinterpret_cast<const int4*>(row + e0);
        const int4* cp = reinterpret_cast<const int4*>(col + e0);
        const int4* vp = reinterpret_cast<const int4*>(reinterpret_cast<const int*>(val) + e0);
        const int* bb = blockbase + blk * NBUCK;
        for (int i = threadIdx.x; i < CH / 4; i += 256) {
            int4 r = rp[i];
            int4 c = cp[i];
            int4 v = vp[i];
            #pragma unroll
            for (int q = 0; q < 4; ++q) {
                int rr = (q == 0) ? r.x : (q == 1) ? r.y : (q == 2) ? r.z : r.w;
                int ccol = (q == 0) ? c.x : (q == 1) ? c.y : (q == 2) ? c.z : c.w;
                int vv = (q == 0) ? v.x : (q == 1) ? v.y : (q == 2) ? v.z : v.w;
                int b = rr >> 7;
                int lr = atomicAdd(&cnt[b], 1);
                int slot = cptr[b] + bb[b] + lr;
                staging[slot] = make_int2((ccol << 7) | (rr & 127), vv);
            }
        }
    } else {
        gemm1_block(blockIdx.x - C_NB, threadIdx.x, X, W1f, H1);
    }
}

// ---------------- Launch B: C4 per-bucket sort (blocks 0..NBUCK-1) | gemm1 half 2 ----------------
// Rows padded to x8 with (col=0,val=0). rowptr[r] = start, rowcnt[r] = exact
// padded count. No row spans the inter-bucket gap.
__global__ __launch_bounds__(256) void fusedB_kernel(const int* __restrict__ cptr,
                                                     const int2* __restrict__ staging,
                                                     int2* __restrict__ edges,
                                                     int* __restrict__ rowptr,
                                                     int* __restrict__ rowcnt,
                                                     const float* __restrict__ X,
                                                     const ushort* __restrict__ W1f,
                                                     ushort* __restrict__ H1) {
    __shared__ int cnt[128];
    __shared__ int sc[128];
    __shared__ int pexcl[129];
    __shared__ int cur[128];
    if (blockIdx.x < NBUCK) {
        const int b = blockIdx.x;
        const int tid = threadIdx.x;
        const int lo = cptr[b], hi = cptr[b + 1];
        const int base = lo + BPAD * b;

        if (tid < 128) cnt[tid] = 0;
        __syncthreads();
        for (int i = lo + tid; i < hi; i += 256) atomicAdd(&cnt[staging[i].x & 127], 1);
        __syncthreads();
        int pv = 0;
        if (tid < 128) { pv = (cnt[tid] + 7) & ~7; sc[tid] = pv; }   // padded bin size
        __syncthreads();
        #pragma unroll
        for (int off = 1; off < 128; off <<= 1) {
            int t = 0;
            if (tid < 128 && tid >= off) t = sc[tid - off];
            __syncthreads();
            if (tid < 128) sc[tid] += t;
            __syncthreads();
        }
        if (tid < 128) { pexcl[tid] = sc[tid] - pv; cur[tid] = sc[tid] - pv; }
        __syncthreads();
        if (tid < 128) {
            int gr = b * 128 + tid;
            if (gr < N_NODES) {
                rowptr[gr] = base + pexcl[tid];
                rowcnt[gr] = pv;                       // exact padded length (x8)
            }
            // zero per-bin pad slots (<=7 each) - these ARE processed as edges
            int s = base + pexcl[tid] + cnt[tid];
            int e = s + (pv - cnt[tid]);
            for (int i = s; i < e; ++i) edges[i] = make_int2(0, 0);
        }
        __syncthreads();
        // scatter real edges
        for (int i = lo + tid; i < hi; i += 256) {
            int2 ev = staging[i];
            int pos = atomicAdd(&cur[ev.x & 127], 1);
            edges[base + pos] = make_int2(ev.x >> 7, ev.y);
        }
    } else {
        gemm1_block(G1_HALF + (blockIdx.x - NBUCK), threadIdx.x, X, W1f, H1);
    }
}

// ---------------- SPMM1 + relu + W2 fused ----------------
// One wave per row; rows padded to x8 -> guard-free unroll-8 loop, 8 gathers
// in flight per iteration.
__global__ __launch_bounds__(256) void spmm1_w2_kernel(const int* __restrict__ rowptr,
                                                       const int* __restrict__ rowcnt,
                                                       const int2* __restrict__ edges,
                                                       const ushort* __restrict__ H1,
                                                       const float* __restrict__ W2,
                                                       ushort* __restrict__ H3) {
    __shared__ float Ws[64 * 40];
    __shared__ float hrow[4][64];
    for (int i = threadIdx.x; i < 64 * 40; i += 256) Ws[i] = W2[i];
    __syncthreads();

    const int r = blockIdx.x * 4 + (threadIdx.x >> 6);
    const int wave = threadIdx.x >> 6;
    const int lane = threadIdx.x & 63;
    if (r >= N_NODES) return;

    const int us = __builtin_amdgcn_readfirstlane(rowptr[r]);
    const int cnt8 = __builtin_amdgcn_readfirstlane(rowcnt[r]);
    const int2* __restrict__ ew = edges + us;

    float acc = 0.f;
    for (int j = 0; j < cnt8; j += 8) {
        int2 e0 = ew[j + 0], e1 = ew[j + 1], e2 = ew[j + 2], e3 = ew[j + 3];
        int2 e4 = ew[j + 4], e5 = ew[j + 5], e6 = ew[j + 6], e7 = ew[j + 7];
        ushort h0 = H1[e0.x * 64 + lane];
        ushort h1 = H1[e1.x * 64 + lane];
        ushort h2 = H1[e2.x * 64 + lane];
        ushort h3 = H1[e3.x * 64 + lane];
        ushort h4 = H1[e4.x * 64 + lane];
        ushort h5 = H1[e5.x * 64 + lane];
        ushort h6 = H1[e6.x * 64 + lane];
        ushort h7 = H1[e7.x * 64 + lane];
        acc = fmaf(__int_as_float(e0.y), bf2f(h0), acc);
        acc = fmaf(__int_as_float(e1.y), bf2f(h1), acc);
        acc = fmaf(__int_as_float(e2.y), bf2f(h2), acc);
        acc = fmaf(__int_as_float(e3.y), bf2f(h3), acc);
        acc = fmaf(__int_as_float(e4.y), bf2f(h4), acc);
        acc = fmaf(__int_as_float(e5.y), bf2f(h5), acc);
        acc = fmaf(__int_as_float(e6.y), bf2f(h6), acc);
        acc = fmaf(__int_as_float(e7.y), bf2f(h7), acc);
    }

    hrow[wave][lane] = fmaxf(acc, 0.f);
    float o = 0.f;
    if (lane < 40) {
        #pragma unroll
        for (int k = 0; k < 64; ++k) o += hrow[wave][k] * Ws[k * 40 + lane];
        H3[(long)r * 40 + lane] = f2bf(o);
    }
}

// ---------------- SPMM2: out[r,0:40] = (A@H3)[r,:] ----------------
__global__ __launch_bounds__(256) void spmm2_kernel(const int* __restrict__ rowptr,
                                                    const int* __restrict__ rowcnt,
                                                    const int2* __restrict__ edges,
                                                    const ushort* __restrict__ H,
                                                    float* __restrict__ O) {
    const int r = blockIdx.x * 4 + (threadIdx.x >> 6);
    if (r >= N_NODES) return;
    const int lane = threadIdx.x & 63;

    const int us = __builtin_amdgcn_readfirstlane(rowptr[r]);
    const int cnt8 = __builtin_amdgcn_readfirstlane(rowcnt[r]);
    const int2* __restrict__ ew = edges + us;

    float acc = 0.f;
    for (int j = 0; j < cnt8; j += 8) {
        int2 e0 = ew[j + 0], e1 = ew[j + 1], e2 = ew[j + 2], e3 = ew[j + 3];
        int2 e4 = ew[j + 4], e5 = ew[j + 5], e6 = ew[j + 6], e7 = ew[j + 7];
        // lanes 40..63 overread into following rows (within ws) - discarded
        ushort h0 = H[e0.x * 40 + lane];
        ushort h1 = H[e1.x * 40 + lane];
        ushort h2 = H[e2.x * 40 + lane];
        ushort h3 = H[e3.x * 40 + lane];
        ushort h4 = H[e4.x * 40 + lane];
        ushort h5 = H[e5.x * 40 + lane];
        ushort h6 = H[e6.x * 40 + lane];
        ushort h7 = H[e7.x * 40 + lane];
        acc = fmaf(__int_as_float(e0.y), bf2f(h0), acc);
        acc = fmaf(__int_as_float(e1.y), bf2f(h1), acc);
        acc = fmaf(__int_as_float(e2.y), bf2f(h2), acc);
        acc = fmaf(__int_as_float(e3.y), bf2f(h3), acc);
        acc = fmaf(__int_as_float(e4.y), bf2f(h4), acc);
        acc = fmaf(__int_as_float(e5.y), bf2f(h5), acc);
        acc = fmaf(__int_as_float(e6.y), bf2f(h6), acc);
        acc = fmaf(__int_as_float(e7.y), bf2f(h7), acc);
    }
    if (lane < 40) O[(long)r * 40 + lane] = acc;
}

extern "C" void kernel_launch(void* const* d_in, const int* in_sizes, int n_in,
                              void* d_out, int out_size, void* d_ws, size_t ws_size,
                              hipStream_t stream) {
    const float* x       = (const float*)d_in[0];
    const float* W1      = (const float*)d_in[1];
    const float* W2      = (const float*)d_in[2];
    const float* adj_val = (const float*)d_in[3];
    const int*   adj_row = (const int*)d_in[4];
    const int*   adj_col = (const int*)d_in[5];
    float* out = (float*)d_out;

    char* ws = (char*)d_ws;
    const size_t OFF_H1     = 0;             // bf16 h1: 12.8 MB
    const size_t OFF_STG    = 12800000;      // int2 staging: 25.6 MB (h3 overlays after C4)
    const size_t OFF_H3     = 12800000;      // bf16 h3: 8 MB
    const size_t OFF_EDGES  = 38400000;      // int2 edges (padded x8): 32,006,144 B
    const size_t OFF_ROWPTR = 70406272;      // 400,000 B
    const size_t OFF_ROWCNT = 70806272;      // 400,000 B
    const size_t OFF_CC     = 71206272;      // 3,136 B
    const size_t OFF_CPTR   = 71209408;      // 3,136 B
    const size_t OFF_BB     = 71212544;      // 256*782*4 = 800,768 B
    const size_t OFF_W1F    = 72013312;      // 65,536 B (16B aligned)

    ushort* h1     = (ushort*)(ws + OFF_H1);
    int2*   stg    = (int2*)(ws + OFF_STG);
    ushort* h3     = (ushort*)(ws + OFF_H3);
    int2*   edges  = (int2*)(ws + OFF_EDGES);
    int*    rowptr = (int*)(ws + OFF_ROWPTR);
    int*    rowcnt = (int*)(ws + OFF_ROWCNT);
    int*    cc     = (int*)(ws + OFF_CC);
    int*    cptr   = (int*)(ws + OFF_CPTR);
    int*    bb     = (int*)(ws + OFF_BB);
    ushort* w1f    = (ushort*)(ws + OFF_W1F);

    // prep: w1cvt + zero coarse counts
    prep_kernel<<<128 + 4, 256, 0, stream>>>(W1, w1f, cc);

    // C1: coarse histogram
    c1_kernel<<<C_NB, 256, 0, stream>>>(adj_row, cc, bb);

    // C2: 782-wide scan
    c2_scan_kernel<<<1, 1024, 0, stream>>>(cc, cptr);

    // Launch A: C3 scatter | gemm1 half 1
    fusedA_kernel<<<C_NB + G1_HALF, 256, 0, stream>>>(adj_row, adj_col, adj_val,
                                                      cptr, bb, stg, x, w1f, h1);

    // Launch B: C4 sort | gemm1 half 2
    fusedB_kernel<<<NBUCK + (G1_NB - G1_HALF), 256, 0, stream>>>(cptr, stg, edges,
                                                                 rowptr, rowcnt, x, w1f, h1);

    // spmm1 + relu + W2 (h2 never materialized)
    spmm1_w2_kernel<<<(N_NODES + 3) / 4, 256, 0, stream>>>(rowptr, rowcnt, edges, h1, W2, h3);

    // spmm2
    spmm2_kernel<<<(N_NODES + 3) / 4, 256, 0, stream>>>(rowptr, rowcnt, edges, h3, out);
}

// Round 14
// 299.151 us; speedup vs baseline: 1.1845x; 1.1845x over previous
//
#include <hip/hip_runtime.h>

#define N_NODES 100000
#define N_EDGES 3200000
#define CH      12500      // edges per chunk (C1/C3)
#define C_NB    256        // chunks; C_NB*CH == N_EDGES exactly
#define NBUCK   782        // ceil(N_NODES/128)
#define G1_NB   1563       // ceil(N_NODES/64)
#define BPAD    1024       // per-bucket padding headroom (max row-pads 7*128=896)

typedef unsigned int uint;
typedef unsigned short ushort;

typedef __attribute__((ext_vector_type(8))) short short8;    // 8 bf16 (4 VGPRs)
typedef __attribute__((ext_vector_type(4))) float floatx4;   // MFMA C/D

static __device__ __forceinline__ ushort f2bf(float f) {     // RNE
    uint u = __float_as_uint(f);
    u += 0x7fffu + ((u >> 16) & 1u);
    return (ushort)(u >> 16);
}
static __device__ __forceinline__ float bf2f(ushort h) {
    return __uint_as_float(((uint)h) << 16);
}

// ---------------- prep: w1cvt (blocks 0..127) + zero coarse_count ----------------
__global__ __launch_bounds__(256) void prep_kernel(const float* __restrict__ W1,
                                                   ushort* __restrict__ W1f,
                                                   int* __restrict__ cc) {
    if (blockIdx.x < 128) {
        int t = blockIdx.x * 256 + threadIdx.x;   // 0..32767
        int j = t & 7;
        int lane = (t >> 3) & 63;
        int tile = t >> 9;
        int kt = tile >> 2, nt = tile & 3;
        int k = kt * 32 + ((lane >> 4) << 3) + j;
        int n = nt * 16 + (lane & 15);
        W1f[t] = f2bf(W1[k * 64 + n]);
    } else {
        int i = (blockIdx.x - 128) * 256 + threadIdx.x;
        if (i < NBUCK) cc[i] = 0;
    }
}

// ---------------- fused: C1 coarse hist (blocks 0..C_NB-1) | gemm1 MFMA ----------------
__global__ __launch_bounds__(256) void fused_g1_c1_kernel(const float* __restrict__ X,
                                                          const ushort* __restrict__ W1f,
                                                          ushort* __restrict__ H1,
                                                          const int* __restrict__ row,
                                                          int* __restrict__ cc,
                                                          int* __restrict__ blockbase) {
    __shared__ int hist[NBUCK];
    if (blockIdx.x < C_NB) {
        const int blk = blockIdx.x;
        for (int i = threadIdx.x; i < NBUCK; i += 256) hist[i] = 0;
        __syncthreads();
        const int4* rp = reinterpret_cast<const int4*>(row + (long)blk * CH);
        for (int i = threadIdx.x; i < CH / 4; i += 256) {
            int4 r = rp[i];
            atomicAdd(&hist[r.x >> 7], 1);
            atomicAdd(&hist[r.y >> 7], 1);
            atomicAdd(&hist[r.z >> 7], 1);
            atomicAdd(&hist[r.w >> 7], 1);
        }
        __syncthreads();
        for (int i = threadIdx.x; i < NBUCK; i += 256) {
            int c = hist[i];
            int base = 0;
            if (c) base = atomicAdd(&cc[i], c);
            blockbase[blk * NBUCK + i] = base;
        }
    } else {
        const int bid = blockIdx.x - C_NB;
        const int tid = threadIdx.x;
        const int wave = tid >> 6;
        const int lane = tid & 63;
        const int arow = bid * 64 + wave * 16 + (lane & 15);
        const bool valid = arow < N_NODES;
        const float* xr = X + (long)arow * 512 + ((lane >> 4) << 3);
        const short8* bb = reinterpret_cast<const short8*>(W1f) + lane;

        floatx4 acc0 = {0.f, 0.f, 0.f, 0.f};
        floatx4 acc1 = {0.f, 0.f, 0.f, 0.f};
        floatx4 acc2 = {0.f, 0.f, 0.f, 0.f};
        floatx4 acc3 = {0.f, 0.f, 0.f, 0.f};

        for (int kt = 0; kt < 16; ++kt) {
            float4 ax0, ax1;
            if (valid) {
                ax0 = *reinterpret_cast<const float4*>(xr + kt * 32);
                ax1 = *reinterpret_cast<const float4*>(xr + kt * 32 + 4);
            } else {
                ax0 = make_float4(0.f, 0.f, 0.f, 0.f);
                ax1 = ax0;
            }
            uint4 ap;
            ap.x = (__float_as_uint(ax0.x) >> 16) | (__float_as_uint(ax0.y) & 0xffff0000u);
            ap.y = (__float_as_uint(ax0.z) >> 16) | (__float_as_uint(ax0.w) & 0xffff0000u);
            ap.z = (__float_as_uint(ax1.x) >> 16) | (__float_as_uint(ax1.y) & 0xffff0000u);
            ap.w = (__float_as_uint(ax1.z) >> 16) | (__float_as_uint(ax1.w) & 0xffff0000u);
            short8 a = *reinterpret_cast<short8*>(&ap);

            const short8* bk = bb + kt * 4 * 64;
            acc0 = __builtin_amdgcn_mfma_f32_16x16x32_bf16(a, bk[0 * 64], acc0, 0, 0, 0);
            acc1 = __builtin_amdgcn_mfma_f32_16x16x32_bf16(a, bk[1 * 64], acc1, 0, 0, 0);
            acc2 = __builtin_amdgcn_mfma_f32_16x16x32_bf16(a, bk[2 * 64], acc2, 0, 0, 0);
            acc3 = __builtin_amdgcn_mfma_f32_16x16x32_bf16(a, bk[3 * 64], acc3, 0, 0, 0);
        }

        const int mrow = bid * 64 + wave * 16 + (lane >> 4) * 4;
        const int ncol = lane & 15;
        #pragma unroll
        for (int r = 0; r < 4; ++r) {
            int orow = mrow + r;
            if (orow < N_NODES) {
                ushort* o = H1 + (long)orow * 64 + ncol;
                o[0]  = f2bf(acc0[r]);
                o[16] = f2bf(acc1[r]);
                o[32] = f2bf(acc2[r]);
                o[48] = f2bf(acc3[r]);
            }
        }
    }
}

// ---------------- C2: scan of 782 coarse counts ----------------
__global__ __launch_bounds__(1024) void c2_scan_kernel(const int* __restrict__ cc,
                                                       int* __restrict__ cptr) {
    __shared__ int sm[1024];
    const int tid = threadIdx.x;
    int v = (tid < NBUCK) ? cc[tid] : 0;
    sm[tid] = v;
    __syncthreads();
    #pragma unroll
    for (int off = 1; off < 1024; off <<= 1) {
        int t = (tid >= off) ? sm[tid - off] : 0;
        __syncthreads();
        sm[tid] += t;
        __syncthreads();
    }
    if (tid < NBUCK) cptr[tid] = sm[tid] - v;        // exclusive
    if (tid == NBUCK - 1) cptr[NBUCK] = sm[tid];     // total = N_EDGES
}

// ---------------- C3: bucket scatter (LDS ranks, block-local runs) ----------------
__global__ __launch_bounds__(256) void c3_kernel(const int* __restrict__ row,
                                                 const int* __restrict__ col,
                                                 const float* __restrict__ val,
                                                 const int* __restrict__ cptr,
                                                 const int* __restrict__ blockbase,
                                                 int2* __restrict__ staging) {
    __shared__ int cnt[NBUCK];
    const int blk = blockIdx.x;
    for (int i = threadIdx.x; i < NBUCK; i += 256) cnt[i] = 0;
    __syncthreads();
    const long e0 = (long)blk * CH;
    const int4* rp = reinterpret_cast<const int4*>(row + e0);
    const int4* cp = reinterpret_cast<const int4*>(col + e0);
    const int4* vp = reinterpret_cast<const int4*>(reinterpret_cast<const int*>(val) + e0);
    const int* bb = blockbase + blk * NBUCK;
    for (int i = threadIdx.x; i < CH / 4; i += 256) {
        int4 r = rp[i];
        int4 c = cp[i];
        int4 v = vp[i];
        #pragma unroll
        for (int q = 0; q < 4; ++q) {
            int rr = (q == 0) ? r.x : (q == 1) ? r.y : (q == 2) ? r.z : r.w;
            int ccol = (q == 0) ? c.x : (q == 1) ? c.y : (q == 2) ? c.z : c.w;
            int vv = (q == 0) ? v.x : (q == 1) ? v.y : (q == 2) ? v.z : v.w;
            int b = rr >> 7;
            int lr = atomicAdd(&cnt[b], 1);
            int slot = cptr[b] + bb[b] + lr;
            staging[slot] = make_int2((ccol << 7) | (rr & 127), vv);
        }
    }
}

// ---------------- C4: per-bucket sort -> PADDED(8) rowptr + rowcnt + final CSR ----------------
// Rows padded to a multiple of 8 with (col=0,val=0). rowptr[r] = start,
// rowcnt[r] = exact padded count. No row spans the inter-bucket gap.
__global__ __launch_bounds__(256) void c4_kernel(const int* __restrict__ cptr,
                                                 const int2* __restrict__ staging,
                                                 int2* __restrict__ edges,
                                                 int* __restrict__ rowptr,
                                                 int* __restrict__ rowcnt) {
    __shared__ int cnt[128];
    __shared__ int sc[128];
    __shared__ int pexcl[129];
    __shared__ int cur[128];
    const int b = blockIdx.x;
    const int tid = threadIdx.x;
    const int lo = cptr[b], hi = cptr[b + 1];
    const int base = lo + BPAD * b;

    if (tid < 128) cnt[tid] = 0;
    __syncthreads();
    for (int i = lo + tid; i < hi; i += 256) atomicAdd(&cnt[staging[i].x & 127], 1);
    __syncthreads();
    int pv = 0;
    if (tid < 128) { pv = (cnt[tid] + 7) & ~7; sc[tid] = pv; }   // padded bin size
    __syncthreads();
    #pragma unroll
    for (int off = 1; off < 128; off <<= 1) {
        int t = 0;
        if (tid < 128 && tid >= off) t = sc[tid - off];
        __syncthreads();
        if (tid < 128) sc[tid] += t;
        __syncthreads();
    }
    if (tid < 128) { pexcl[tid] = sc[tid] - pv; cur[tid] = sc[tid] - pv; }
    __syncthreads();
    if (tid < 128) {
        int gr = b * 128 + tid;
        if (gr < N_NODES) {
            rowptr[gr] = base + pexcl[tid];
            rowcnt[gr] = pv;                       // exact padded length (x8)
        }
        // zero per-bin pad slots (<=7 each) - these ARE processed as edges
        int s = base + pexcl[tid] + cnt[tid];
        int e = s + (pv - cnt[tid]);
        for (int i = s; i < e; ++i) edges[i] = make_int2(0, 0);
    }
    __syncthreads();
    // scatter real edges
    for (int i = lo + tid; i < hi; i += 256) {
        int2 ev = staging[i];
        int pos = atomicAdd(&cur[ev.x & 127], 1);
        edges[base + pos] = make_int2(ev.x >> 7, ev.y);
    }
}

// ---------------- SPMM1 + relu + W2 fused ----------------
// One wave per row; rows padded to x8 -> guard-free unroll-8 loop, 8 gathers
// in flight per iteration. H3 written with PADDED 64-wide rows (feats 40..63
// zero) so spmm2's gathers are 128B-aligned.
__global__ __launch_bounds__(256) void spmm1_w2_kernel(const int* __restrict__ rowptr,
                                                       const int* __restrict__ rowcnt,
                                                       const int2* __restrict__ edges,
                                                       const ushort* __restrict__ H1,
                                                       const float* __restrict__ W2,
                                                       ushort* __restrict__ H3) {
    __shared__ float Ws[64 * 40];
    __shared__ float hrow[4][64];
    for (int i = threadIdx.x; i < 64 * 40; i += 256) Ws[i] = W2[i];
    __syncthreads();

    const int r = blockIdx.x * 4 + (threadIdx.x >> 6);
    const int wave = threadIdx.x >> 6;
    const int lane = threadIdx.x & 63;
    if (r >= N_NODES) return;

    const int us = __builtin_amdgcn_readfirstlane(rowptr[r]);
    const int cnt8 = __builtin_amdgcn_readfirstlane(rowcnt[r]);
    const int2* __restrict__ ew = edges + us;

    float acc = 0.f;
    for (int j = 0; j < cnt8; j += 8) {
        int2 e0 = ew[j + 0], e1 = ew[j + 1], e2 = ew[j + 2], e3 = ew[j + 3];
        int2 e4 = ew[j + 4], e5 = ew[j + 5], e6 = ew[j + 6], e7 = ew[j + 7];
        ushort h0 = H1[e0.x * 64 + lane];
        ushort h1 = H1[e1.x * 64 + lane];
        ushort h2 = H1[e2.x * 64 + lane];
        ushort h3 = H1[e3.x * 64 + lane];
        ushort h4 = H1[e4.x * 64 + lane];
        ushort h5 = H1[e5.x * 64 + lane];
        ushort h6 = H1[e6.x * 64 + lane];
        ushort h7 = H1[e7.x * 64 + lane];
        acc = fmaf(__int_as_float(e0.y), bf2f(h0), acc);
        acc = fmaf(__int_as_float(e1.y), bf2f(h1), acc);
        acc = fmaf(__int_as_float(e2.y), bf2f(h2), acc);
        acc = fmaf(__int_as_float(e3.y), bf2f(h3), acc);
        acc = fmaf(__int_as_float(e4.y), bf2f(h4), acc);
        acc = fmaf(__int_as_float(e5.y), bf2f(h5), acc);
        acc = fmaf(__int_as_float(e6.y), bf2f(h6), acc);
        acc = fmaf(__int_as_float(e7.y), bf2f(h7), acc);
    }

    hrow[wave][lane] = fmaxf(acc, 0.f);
    float o = 0.f;
    if (lane < 40) {
        #pragma unroll
        for (int k = 0; k < 64; ++k) o += hrow[wave][k] * Ws[k * 40 + lane];
    }
    // padded 64-wide row: lanes 40..63 store 0 (keeps spmm2 gathers aligned)
    H3[(long)r * 64 + lane] = (lane < 40) ? f2bf(o) : (ushort)0;
}

// ---------------- SPMM2: out[r,0:40] = (A@H3)[r,:], H3 rows padded to 64 ----------------
__global__ __launch_bounds__(256) void spmm2_kernel(const int* __restrict__ rowptr,
                                                    const int* __restrict__ rowcnt,
                                                    const int2* __restrict__ edges,
                                                    const ushort* __restrict__ H,
                                                    float* __restrict__ O) {
    const int r = blockIdx.x * 4 + (threadIdx.x >> 6);
    if (r >= N_NODES) return;
    const int lane = threadIdx.x & 63;

    const int us = __builtin_amdgcn_readfirstlane(rowptr[r]);
    const int cnt8 = __builtin_amdgcn_readfirstlane(rowcnt[r]);
    const int2* __restrict__ ew = edges + us;

    float acc = 0.f;
    for (int j = 0; j < cnt8; j += 8) {
        int2 e0 = ew[j + 0], e1 = ew[j + 1], e2 = ew[j + 2], e3 = ew[j + 3];
        int2 e4 = ew[j + 4], e5 = ew[j + 5], e6 = ew[j + 6], e7 = ew[j + 7];
        // aligned 128B gathers (padded rows); lanes 40..63 read zeros
        ushort h0 = H[e0.x * 64 + lane];
        ushort h1 = H[e1.x * 64 + lane];
        ushort h2 = H[e2.x * 64 + lane];
        ushort h3 = H[e3.x * 64 + lane];
        ushort h4 = H[e4.x * 64 + lane];
        ushort h5 = H[e5.x * 64 + lane];
        ushort h6 = H[e6.x * 64 + lane];
        ushort h7 = H[e7.x * 64 + lane];
        acc = fmaf(__int_as_float(e0.y), bf2f(h0), acc);
        acc = fmaf(__int_as_float(e1.y), bf2f(h1), acc);
        acc = fmaf(__int_as_float(e2.y), bf2f(h2), acc);
        acc = fmaf(__int_as_float(e3.y), bf2f(h3), acc);
        acc = fmaf(__int_as_float(e4.y), bf2f(h4), acc);
        acc = fmaf(__int_as_float(e5.y), bf2f(h5), acc);
        acc = fmaf(__int_as_float(e6.y), bf2f(h6), acc);
        acc = fmaf(__int_as_float(e7.y), bf2f(h7), acc);
    }
    if (lane < 40) O[(long)r * 40 + lane] = acc;
}

extern "C" void kernel_launch(void* const* d_in, const int* in_sizes, int n_in,
                              void* d_out, int out_size, void* d_ws, size_t ws_size,
                              hipStream_t stream) {
    const float* x       = (const float*)d_in[0];
    const float* W1      = (const float*)d_in[1];
    const float* W2      = (const float*)d_in[2];
    const float* adj_val = (const float*)d_in[3];
    const int*   adj_row = (const int*)d_in[4];
    const int*   adj_col = (const int*)d_in[5];
    float* out = (float*)d_out;

    char* ws = (char*)d_ws;
    const size_t OFF_H1     = 0;             // bf16 h1: 12.8 MB
    const size_t OFF_STG    = 12800000;      // int2 staging: 25.6 MB (h3 overlays after C4)
    const size_t OFF_H3     = 12800000;      // bf16 h3 (64-wide padded): 12.8 MB
    const size_t OFF_EDGES  = 38400000;      // int2 edges (padded x8): 32,006,144 B
    const size_t OFF_ROWPTR = 70406272;      // 400,000 B
    const size_t OFF_ROWCNT = 70806272;      // 400,000 B
    const size_t OFF_CC     = 71206272;      // 3,136 B
    const size_t OFF_CPTR   = 71209408;      // 3,136 B
    const size_t OFF_BB     = 71212544;      // 256*782*4 = 800,768 B
    const size_t OFF_W1F    = 72013312;      // 65,536 B (16B aligned)

    ushort* h1     = (ushort*)(ws + OFF_H1);
    int2*   stg    = (int2*)(ws + OFF_STG);
    ushort* h3     = (ushort*)(ws + OFF_H3);
    int2*   edges  = (int2*)(ws + OFF_EDGES);
    int*    rowptr = (int*)(ws + OFF_ROWPTR);
    int*    rowcnt = (int*)(ws + OFF_ROWCNT);
    int*    cc     = (int*)(ws + OFF_CC);
    int*    cptr   = (int*)(ws + OFF_CPTR);
    int*    bb     = (int*)(ws + OFF_BB);
    ushort* w1f    = (ushort*)(ws + OFF_W1F);

    // prep: w1cvt + zero coarse counts
    prep_kernel<<<128 + 4, 256, 0, stream>>>(W1, w1f, cc);

    // fused: gemm1 (MFMA, HBM-stream) | C1 coarse hist (LDS, few atomics)
    fused_g1_c1_kernel<<<C_NB + G1_NB, 256, 0, stream>>>(x, w1f, h1, adj_row, cc, bb);

    // C2: 782-wide scan
    c2_scan_kernel<<<1, 1024, 0, stream>>>(cc, cptr);

    // C3: scatter into coarse buckets (block-local runs)
    c3_kernel<<<C_NB, 256, 0, stream>>>(adj_row, adj_col, adj_val, cptr, bb, stg);

    // C4: per-bucket sort -> padded(8) rowptr + rowcnt + final CSR
    c4_kernel<<<NBUCK, 256, 0, stream>>>(cptr, stg, edges, rowptr, rowcnt);

    // spmm1 + relu + W2 (h2 never materialized; h3 64-wide padded)
    spmm1_w2_kernel<<<(N_NODES + 3) / 4, 256, 0, stream>>>(rowptr, rowcnt, edges, h1, W2, h3);

    // spmm2
    spmm2_kernel<<<(N_NODES + 3) / 4, 256, 0, stream>>>(rowptr, rowcnt, edges, h3, out);
}